// Round 1
// baseline (60.546 us; speedup 1.0000x reference)
//
#include <hip/hip_runtime.h>

// Problem constants (fixed by the reference)
#define NXY   16
#define NZ    8
#define NS    2048      // states = 16*16*8
#define NT    2048      // tokens
#define NB    16        // stories
#define NL    16        // story length
#define NSENT 16        // tokens per sentence
#define NEGV  (-1e9f)

// ---------------------------------------------------------------------------
// K1: fused x-smooth + y-smooth + transpose.
// emissions [Z,Y,X,T] (row-major, t contiguous)  ->  em_T [T, S]  (s = x+16y+256z)
// Block handles one z-slice and a 32-token tile: all 256 (y,x) are present so
// the clamped 5-wide windows need no halo.
// ---------------------------------------------------------------------------
#define TT 32

__device__ __forceinline__ float lse5(float v0, float v1, float v2, float v3, float v4) {
    float m = fmaxf(fmaxf(fmaxf(v0, v1), fmaxf(v2, v3)), v4);
    float s = __expf(v0 - m) + __expf(v1 - m) + __expf(v2 - m) + __expf(v3 - m) + __expf(v4 - m);
    return m + __logf(s);
}

__global__ __launch_bounds__(256) void k_smooth(const float* __restrict__ em,
                                                float* __restrict__ emT) {
    __shared__ float A[256 * 33];   // [xy][tt], pad 33 -> conflict-free
    __shared__ float Bs[256 * 33];
    const int tid = threadIdx.x;
    const int t0 = blockIdx.x * TT;
    const int z = blockIdx.y;

    // load 256 (y,x) rows x 32 tokens, float4-vectorized on t
    const float* base = em + (size_t)z * 256 * NT + t0;
#pragma unroll
    for (int i = 0; i < 8; ++i) {
        int fi = i * 256 + tid;
        int xy = fi >> 3;
        int c = (fi & 7) << 2;
        float4 v = *(const float4*)(base + (size_t)xy * NT + c);
        float* dst = &A[xy * 33 + c];
        dst[0] = v.x; dst[1] = v.y; dst[2] = v.z; dst[3] = v.w;
    }
    __syncthreads();

    const float LOG5 = 1.6094379124341003f;
    const int x = tid & 15, y = tid >> 4;

    // smooth along x (replicate clamp)
    int r[5];
#pragma unroll
    for (int k = 0; k < 5; ++k) {
        int xx = x + k - 2; xx = xx < 0 ? 0 : (xx > 15 ? 15 : xx);
        r[k] = (y * 16 + xx) * 33;
    }
#pragma unroll
    for (int tt = 0; tt < TT; ++tt) {
        Bs[tid * 33 + tt] =
            lse5(A[r[0] + tt], A[r[1] + tt], A[r[2] + tt], A[r[3] + tt], A[r[4] + tt]) - LOG5;
    }
    __syncthreads();

    // smooth along y + transposed write
#pragma unroll
    for (int k = 0; k < 5; ++k) {
        int yy = y + k - 2; yy = yy < 0 ? 0 : (yy > 15 ? 15 : yy);
        r[k] = (yy * 16 + x) * 33;
    }
    float* ob = emT + (size_t)t0 * NS + z * 256 + tid;
#pragma unroll
    for (int tt = 0; tt < TT; ++tt) {
        ob[(size_t)tt * NS] =
            lse5(Bs[r[0] + tt], Bs[r[1] + tt], Bs[r[2] + tt], Bs[r[3] + tt], Bs[r[4] + tt]) - LOG5;
    }
}

// ---------------------------------------------------------------------------
// K2: e_all[b,l,s] = sum_j em_T[tok[b,l,j], s]   (contiguous row reads)
// ---------------------------------------------------------------------------
__global__ __launch_bounds__(256) void k_eall(const int* __restrict__ stories,
                                              const float* __restrict__ emT,
                                              float* __restrict__ eall) {
    const int bl = blockIdx.x;          // b*NL + l
    const int tid = threadIdx.x;
    __shared__ int toks[NSENT];
    if (tid < NSENT) toks[tid] = stories[bl * NSENT + tid];
    __syncthreads();

    float4 a0 = make_float4(0.f, 0.f, 0.f, 0.f);
    float4 a1 = make_float4(0.f, 0.f, 0.f, 0.f);
    for (int j = 0; j < NSENT; ++j) {
        const float4* row = (const float4*)(emT + (size_t)toks[j] * NS);
        float4 v0 = row[tid];
        float4 v1 = row[256 + tid];
        a0.x += v0.x; a0.y += v0.y; a0.z += v0.z; a0.w += v0.w;
        a1.x += v1.x; a1.y += v1.y; a1.z += v1.z; a1.w += v1.w;
    }
    float4* o = (float4*)(eall + (size_t)bl * NS);
    o[tid] = a0;
    o[256 + tid] = a1;
}

// ---------------------------------------------------------------------------
// K3: forward recursion, one block per story. prev/cur state in LDS, the
// sparse (<=7 incoming neighbors) transition row weights cached in LDS.
// next[h] = e[h] + lse_i(w[h,i] + prev[i]) over i in {h, h±1, h±16, h+256, h+512}
// ---------------------------------------------------------------------------
__global__ __launch_bounds__(1024) void k_forward(const float* __restrict__ trans,
                                                  const float* __restrict__ priors,
                                                  const float* __restrict__ eall,
                                                  float* __restrict__ out) {
    __shared__ float w[7][NS];      // 57.3 KB
    __shared__ float buf0[NS];      // 8 KB
    __shared__ float buf1[NS];      // 8 KB
    const int b = blockIdx.x;
    const int tid = threadIdx.x;

    for (int h = tid; h < NS; h += 1024) {
        const int x = h & 15, y = (h >> 4) & 15, z = h >> 8;
        const float* row = trans + (size_t)h * NS;
        w[0][h] = row[h];
        w[1][h] = (x < 15) ? row[h + 1]   : NEGV;
        w[2][h] = (x > 0)  ? row[h - 1]   : NEGV;
        w[3][h] = (y < 15) ? row[h + 16]  : NEGV;
        w[4][h] = (y > 0)  ? row[h - 16]  : NEGV;
        w[5][h] = (z < 7)  ? row[h + 256] : NEGV;
        w[6][h] = (z < 6)  ? row[h + 512] : NEGV;
        float v = eall[(size_t)b * NL * NS + h] + priors[h];
        buf0[h] = v;
        out[(size_t)b * NS + h] = v;          // out[0][b][h]
    }
    __syncthreads();

    float* prev = buf0;
    float* cur = buf1;
    for (int l = 1; l < NL; ++l) {
        const float* e = eall + ((size_t)b * NL + l) * NS;
        for (int h = tid; h < NS; h += 1024) {
            const int x = h & 15, y = (h >> 4) & 15, z = h >> 8;
            float v0 = w[0][h] + prev[h];
            float v1 = w[1][h] + prev[x < 15 ? h + 1   : h];
            float v2 = w[2][h] + prev[x > 0  ? h - 1   : h];
            float v3 = w[3][h] + prev[y < 15 ? h + 16  : h];
            float v4 = w[4][h] + prev[y > 0  ? h - 16  : h];
            float v5 = w[5][h] + prev[z < 7  ? h + 256 : h];
            float v6 = w[6][h] + prev[z < 6  ? h + 512 : h];
            float m = fmaxf(fmaxf(fmaxf(v0, v1), fmaxf(v2, v3)),
                            fmaxf(fmaxf(v4, v5), v6));
            float s = __expf(v0 - m) + __expf(v1 - m) + __expf(v2 - m) + __expf(v3 - m) +
                      __expf(v4 - m) + __expf(v5 - m) + __expf(v6 - m);
            float v = e[h] + m + __logf(s);
            cur[h] = v;
            out[((size_t)l * NB + b) * NS + h] = v;
        }
        __syncthreads();
        float* tmp = prev; prev = cur; cur = tmp;
    }
}

// ---------------------------------------------------------------------------
extern "C" void kernel_launch(void* const* d_in, const int* in_sizes, int n_in,
                              void* d_out, int out_size, void* d_ws, size_t ws_size,
                              hipStream_t stream) {
    (void)in_sizes; (void)n_in; (void)out_size; (void)ws_size;
    const int* stories  = (const int*)d_in[0];
    // d_in[1] = story_length (== NL), unused
    const float* priors = (const float*)d_in[2];
    const float* trans  = (const float*)d_in[3];
    const float* em     = (const float*)d_in[4];
    float* out = (float*)d_out;

    float* emT  = (float*)d_ws;                    // [NT][NS]  16 MB
    float* eall = emT + (size_t)NT * NS;           // [NB*NL][NS]  2 MB

    k_smooth<<<dim3(NT / TT, NZ), 256, 0, stream>>>(em, emT);
    k_eall<<<dim3(NB * NL), 256, 0, stream>>>(stories, emT, eall);
    k_forward<<<dim3(NB), 1024, 0, stream>>>(trans, priors, eall, out);
}

// Round 2
// 48.318 us; speedup vs baseline: 1.2531x; 1.2531x over previous
//
#include <hip/hip_runtime.h>

// Problem constants (fixed by the reference)
#define NXY   16
#define NZ    8
#define NS    2048      // states = 16*16*8
#define NT    2048      // tokens
#define NB    16        // stories
#define NL    16        // story length
#define NSENT 16        // tokens per sentence
#define NEGV  (-1e9f)

// ---------------------------------------------------------------------------
// K1: fused smoothing + transpose.
// Identity: windowed log-mean along x then y ==
//           log( boxmean_y( boxmean_x( exp(em) ) ) )
// so: exp once at load, plain 5-term box sums (replicate-clamped), one log at
// the transposed write. 12x fewer transcendentals than per-window lse.
// Block = one z-slice x 16-token tile; single LDS buffer + register staging.
// ---------------------------------------------------------------------------
#define TT   16
#define LPAD 17          // odd pad -> conflict-free stride

__global__ __launch_bounds__(256) void k_smooth(const float* __restrict__ em,
                                                float* __restrict__ emT) {
    __shared__ float A[256 * LPAD];   // 17.4 KB
    const int tid = threadIdx.x;
    const int t0 = blockIdx.x * TT;
    const int z = blockIdx.y;

    // load 256 (y,x) rows x 16 tokens, float4-coalesced, exp at store
    const float* base = em + (size_t)z * 256 * NT + t0;
#pragma unroll
    for (int i = 0; i < 4; ++i) {
        int f = (i * 256 + tid) * 4;
        int xy = f >> 4;
        int c = f & 15;
        float4 v = *(const float4*)(base + (size_t)xy * NT + c);
        float* dst = &A[xy * LPAD + c];
        dst[0] = __expf(v.x); dst[1] = __expf(v.y);
        dst[2] = __expf(v.z); dst[3] = __expf(v.w);
    }
    __syncthreads();

    const int x = tid & 15, y = tid >> 4;

    // x-pass: 5-term box sum into registers
    int r[5];
#pragma unroll
    for (int k = 0; k < 5; ++k) {
        int xx = x + k - 2; xx = xx < 0 ? 0 : (xx > 15 ? 15 : xx);
        r[k] = (y * 16 + xx) * LPAD;
    }
    float rx[TT];
#pragma unroll
    for (int tt = 0; tt < TT; ++tt)
        rx[tt] = A[r[0] + tt] + A[r[1] + tt] + A[r[2] + tt] + A[r[3] + tt] + A[r[4] + tt];
    __syncthreads();

    // write back in place
#pragma unroll
    for (int tt = 0; tt < TT; ++tt) A[tid * LPAD + tt] = rx[tt];
    __syncthreads();

    // y-pass + log + transposed write
#pragma unroll
    for (int k = 0; k < 5; ++k) {
        int yy = y + k - 2; yy = yy < 0 ? 0 : (yy > 15 ? 15 : yy);
        r[k] = (yy * 16 + x) * LPAD;
    }
    const float LOG25 = 3.2188758248682006f;   // log(5)+log(5)
    float* ob = emT + (size_t)t0 * NS + z * 256 + tid;
#pragma unroll
    for (int tt = 0; tt < TT; ++tt) {
        float s = A[r[0] + tt] + A[r[1] + tt] + A[r[2] + tt] + A[r[3] + tt] + A[r[4] + tt];
        ob[(size_t)tt * NS] = __logf(s) - LOG25;
    }
}

// ---------------------------------------------------------------------------
// K2: e_all[b,l,s] = sum_j em_T[tok[b,l,j], s]   (contiguous row reads)
// grid (256 sentences, 2 halves of the state vector) for 2 blocks/CU
// ---------------------------------------------------------------------------
__global__ __launch_bounds__(256) void k_eall(const int* __restrict__ stories,
                                              const float* __restrict__ emT,
                                              float* __restrict__ eall) {
    const int bl = blockIdx.x;          // b*NL + l
    const int col = blockIdx.y * 256 + threadIdx.x;   // float4 index, 0..511
    __shared__ int toks[NSENT];
    if (threadIdx.x < NSENT) toks[threadIdx.x] = stories[bl * NSENT + threadIdx.x];
    __syncthreads();

    float4 a = make_float4(0.f, 0.f, 0.f, 0.f);
#pragma unroll 4
    for (int j = 0; j < NSENT; ++j) {
        float4 v = ((const float4*)(emT + (size_t)toks[j] * NS))[col];
        a.x += v.x; a.y += v.y; a.z += v.z; a.w += v.w;
    }
    ((float4*)(eall + (size_t)bl * NS))[col] = a;
}

// ---------------------------------------------------------------------------
// K3: forward recursion, one block per story; prev/cur vectors ping-pong in
// LDS; the <=7 sparse incoming weights + clamped neighbor indices live in
// registers (fixed across all 15 steps).
// ---------------------------------------------------------------------------
__global__ __launch_bounds__(1024) void k_forward(const float* __restrict__ trans,
                                                  const float* __restrict__ priors,
                                                  const float* __restrict__ eall,
                                                  float* __restrict__ out) {
    __shared__ float buf0[NS];      // 8 KB
    __shared__ float buf1[NS];      // 8 KB
    const int b = blockIdx.x;
    const int tid = threadIdx.x;

    float wr[2][7];
    int   ix[2][7];
#pragma unroll
    for (int p = 0; p < 2; ++p) {
        const int h = tid + p * 1024;
        const int x = h & 15, y = (h >> 4) & 15, z = h >> 8;
        const float* row = trans + (size_t)h * NS;
        wr[p][0] = row[h];                          ix[p][0] = h;
        wr[p][1] = (x < 15) ? row[h + 1]   : NEGV;  ix[p][1] = (x < 15) ? h + 1   : h;
        wr[p][2] = (x > 0)  ? row[h - 1]   : NEGV;  ix[p][2] = (x > 0)  ? h - 1   : h;
        wr[p][3] = (y < 15) ? row[h + 16]  : NEGV;  ix[p][3] = (y < 15) ? h + 16  : h;
        wr[p][4] = (y > 0)  ? row[h - 16]  : NEGV;  ix[p][4] = (y > 0)  ? h - 16  : h;
        wr[p][5] = (z < 7)  ? row[h + 256] : NEGV;  ix[p][5] = (z < 7)  ? h + 256 : h;
        wr[p][6] = (z < 6)  ? row[h + 512] : NEGV;  ix[p][6] = (z < 6)  ? h + 512 : h;
        float v = eall[(size_t)b * NL * NS + h] + priors[h];
        buf0[h] = v;
        out[(size_t)b * NS + h] = v;          // out[0][b][h]
    }
    __syncthreads();

    float* prev = buf0;
    float* cur = buf1;
    for (int l = 1; l < NL; ++l) {
        const float* e = eall + ((size_t)b * NL + l) * NS;
#pragma unroll
        for (int p = 0; p < 2; ++p) {
            const int h = tid + p * 1024;
            float v0 = wr[p][0] + prev[ix[p][0]];
            float v1 = wr[p][1] + prev[ix[p][1]];
            float v2 = wr[p][2] + prev[ix[p][2]];
            float v3 = wr[p][3] + prev[ix[p][3]];
            float v4 = wr[p][4] + prev[ix[p][4]];
            float v5 = wr[p][5] + prev[ix[p][5]];
            float v6 = wr[p][6] + prev[ix[p][6]];
            float m = fmaxf(fmaxf(fmaxf(v0, v1), fmaxf(v2, v3)),
                            fmaxf(fmaxf(v4, v5), v6));
            float s = __expf(v0 - m) + __expf(v1 - m) + __expf(v2 - m) + __expf(v3 - m) +
                      __expf(v4 - m) + __expf(v5 - m) + __expf(v6 - m);
            float v = e[h] + m + __logf(s);
            cur[h] = v;
            out[((size_t)l * NB + b) * NS + h] = v;
        }
        __syncthreads();
        float* tmp = prev; prev = cur; cur = tmp;
    }
}

// ---------------------------------------------------------------------------
extern "C" void kernel_launch(void* const* d_in, const int* in_sizes, int n_in,
                              void* d_out, int out_size, void* d_ws, size_t ws_size,
                              hipStream_t stream) {
    (void)in_sizes; (void)n_in; (void)out_size; (void)ws_size;
    const int* stories  = (const int*)d_in[0];
    // d_in[1] = story_length (== NL), unused
    const float* priors = (const float*)d_in[2];
    const float* trans  = (const float*)d_in[3];
    const float* em     = (const float*)d_in[4];
    float* out = (float*)d_out;

    float* emT  = (float*)d_ws;                    // [NT][NS]  16 MB
    float* eall = emT + (size_t)NT * NS;           // [NB*NL][NS]  2 MB

    k_smooth<<<dim3(NT / TT, NZ), 256, 0, stream>>>(em, emT);
    k_eall<<<dim3(NB * NL, 2), 256, 0, stream>>>(stories, emT, eall);
    k_forward<<<dim3(NB), 1024, 0, stream>>>(trans, priors, eall, out);
}